// Round 1
// baseline (11859.039 us; speedup 1.0000x reference)
//
#include <hip/hip_runtime.h>

// VGG16-A spiking NN, multi-compartment LIF (K=2), T=3, B=4, fp32.
// Inputs: d_in[0]=x[4,3,32,32]; d_in[1..13]=conv w (OIHW); d_in[14]=fc0[4096,2048];
// d_in[15]=fc1[4096,4096]; d_in[16]=fc2[10,4096]; d_in[17]=thr[15]; d_in[18]=leak[15].
// Output: logits [4,10] fp32, accumulated over T=3 timesteps.

#define BATCH 4

__device__ __forceinline__ float lif_update(float mem_in, float syn, float thr,
                                            float leak, float* mem_out) {
    float m = leak * mem_in + syn;
    float val = 0.f;
    // compartment 0: fires if m/thr - 1 > 0 and 1 - m/(2 thr) >= 0
    if ((m / thr - 1.f > 0.f) && (1.f - m / (2.f * thr) >= 0.f)) val += 1.f;
    // compartment 1: fires if m/(2 thr) - 1 > 0 and 1 - m/(4 thr) >= 0
    if ((m / (2.f * thr) - 1.f > 0.f) && (1.f - m / (4.f * thr) >= 0.f)) val += 2.f;
    *mem_out = m - thr * val;
    return val;
}

__global__ void conv_lif_kernel(const float* __restrict__ in,
                                const float* __restrict__ w,
                                float* __restrict__ mem,
                                float* __restrict__ out,
                                const float* __restrict__ thr_v,
                                const float* __restrict__ leak_v,
                                int layer, int IC, int OC, int H, int W, int n) {
    int idx = blockIdx.x * blockDim.x + threadIdx.x;
    if (idx >= n) return;
    int x  = idx % W;
    int y  = (idx / W) % H;
    int oc = (idx / (W * H)) % OC;
    int b  = idx / (W * H * OC);

    const float* wp = w + (size_t)oc * IC * 9;
    const float* ip = in + (size_t)b * IC * H * W;

    float syn = 0.f;
    for (int ic = 0; ic < IC; ++ic) {
        const float* ipc = ip + (size_t)ic * H * W;
        const float* wpc = wp + ic * 9;
#pragma unroll
        for (int ky = 0; ky < 3; ++ky) {
            int yy = y + ky - 1;
            if (yy < 0 || yy >= H) continue;
#pragma unroll
            for (int kx = 0; kx < 3; ++kx) {
                int xx = x + kx - 1;
                if (xx < 0 || xx >= W) continue;
                syn = fmaf(ipc[yy * W + xx], wpc[ky * 3 + kx], syn);
            }
        }
    }
    float thr = thr_v[layer];
    float leak = leak_v[layer];
    float mo;
    float val = lif_update(mem[idx], syn, thr, leak, &mo);
    mem[idx] = mo;
    out[idx] = val;
}

__global__ void avgpool_kernel(const float* __restrict__ in,
                               float* __restrict__ out,
                               int C, int Ho, int Wo, int n) {
    int idx = blockIdx.x * blockDim.x + threadIdx.x;
    if (idx >= n) return;
    int x = idx % Wo;
    int y = (idx / Wo) % Ho;
    int c = (idx / (Wo * Ho)) % C;
    int b = idx / (Wo * Ho * C);
    int Wi = Wo * 2, Hi = Ho * 2;
    const float* ip = in + ((size_t)b * C + c) * Hi * Wi;
    float s = ip[(2 * y) * Wi + 2 * x] + ip[(2 * y) * Wi + 2 * x + 1] +
              ip[(2 * y + 1) * Wi + 2 * x] + ip[(2 * y + 1) * Wi + 2 * x + 1];
    out[idx] = s * 0.25f;
}

__global__ void fc_lif_kernel(const float* __restrict__ in,
                              const float* __restrict__ w,
                              float* __restrict__ mem,
                              float* __restrict__ out,
                              const float* __restrict__ thr_v,
                              const float* __restrict__ leak_v,
                              int layer, int Kd, int N, int n) {
    int idx = blockIdx.x * blockDim.x + threadIdx.x;
    if (idx >= n) return;
    int j = idx % N;
    int b = idx / N;
    const float* ip = in + (size_t)b * Kd;
    const float* wp = w + (size_t)j * Kd;
    float syn = 0.f;
    for (int k = 0; k < Kd; ++k) syn = fmaf(ip[k], wp[k], syn);
    float thr = thr_v[layer];
    float leak = leak_v[layer];
    float mo;
    float val = lif_update(mem[idx], syn, thr, leak, &mo);
    mem[idx] = mo;
    out[idx] = val;
}

// One 64-thread block per (b, label). logits += in[b,:] . w[l,:]
__global__ void fc2_acc_kernel(const float* __restrict__ in,
                               const float* __restrict__ w,
                               float* __restrict__ logits,
                               int Kd, int L) {
    int o = blockIdx.x;       // 0..B*L-1
    int l = o % L;
    int b = o / L;
    const float* ip = in + (size_t)b * Kd;
    const float* wp = w + (size_t)l * Kd;
    float s = 0.f;
    for (int k = threadIdx.x; k < Kd; k += 64) s = fmaf(ip[k], wp[k], s);
#pragma unroll
    for (int off = 32; off > 0; off >>= 1) s += __shfl_down(s, off);
    if (threadIdx.x == 0) logits[o] += s;
}

extern "C" void kernel_launch(void* const* d_in, const int* in_sizes, int n_in,
                              void* d_out, int out_size, void* d_ws, size_t ws_size,
                              hipStream_t stream) {
    const float* x = (const float*)d_in[0];
    const float* convw[13];
    for (int i = 0; i < 13; ++i) convw[i] = (const float*)d_in[1 + i];
    const float* fc0 = (const float*)d_in[14];
    const float* fc1 = (const float*)d_in[15];
    const float* fc2 = (const float*)d_in[16];
    const float* thr = (const float*)d_in[17];
    const float* leak = (const float*)d_in[18];

    static const int IC[13] = {3, 64, 64, 128, 128, 256, 256, 256, 512, 512, 512, 512, 512};
    static const int OC[13] = {64, 64, 128, 128, 256, 256, 256, 512, 512, 512, 512, 512, 512};
    static const int HH[13] = {32, 32, 16, 16, 8, 8, 8, 4, 4, 4, 2, 2, 2};
    static const bool PA[13] = {false, true, false, true, false, false, true,
                                false, false, true, false, false, false};

    // workspace layout (floats)
    float* ws = (float*)d_ws;
    size_t off = 0;
    float* convmem[13];
    for (int i = 0; i < 13; ++i) {
        convmem[i] = ws + off;
        off += (size_t)BATCH * OC[i] * HH[i] * HH[i];
    }
    float* mfc0 = ws + off; off += BATCH * 4096;
    float* mfc1 = ws + off; off += BATCH * 4096;
    size_t mem_floats = off;
    float* bufs[3];
    for (int i = 0; i < 3; ++i) { bufs[i] = ws + off; off += 262144; }

    // zero membranes (ws is poisoned 0xAA before every call) and logits
    hipMemsetAsync(d_ws, 0, mem_floats * sizeof(float), stream);
    hipMemsetAsync(d_out, 0, (size_t)out_size * sizeof(float), stream);

    for (int t = 0; t < 3; ++t) {
        const float* src = x;
        int cur = -1;  // buffer index holding src; -1 = x
        for (int i = 0; i < 13; ++i) {
            int d = (cur + 1) % 3;
            if (cur < 0) d = 0;
            int n = BATCH * OC[i] * HH[i] * HH[i];
            conv_lif_kernel<<<(n + 255) / 256, 256, 0, stream>>>(
                src, convw[i], convmem[i], bufs[d], thr, leak, i,
                IC[i], OC[i], HH[i], HH[i], n);
            cur = d; src = bufs[cur];
            if (PA[i]) {
                int p = (cur + 1) % 3;
                int Ho = HH[i] / 2;
                int np = BATCH * OC[i] * Ho * Ho;
                avgpool_kernel<<<(np + 255) / 256, 256, 0, stream>>>(
                    src, bufs[p], OC[i], Ho, Ho, np);
                cur = p; src = bufs[p];
            }
        }
        // src now holds [4, 512, 2, 2] = [4, 2048] flattened (NCHW flat == reshape)
        {
            int d = (cur + 1) % 3;
            int n = BATCH * 4096;
            fc_lif_kernel<<<(n + 255) / 256, 256, 0, stream>>>(
                src, fc0, mfc0, bufs[d], thr, leak, 13, 2048, 4096, n);
            cur = d; src = bufs[cur];
        }
        {
            int d = (cur + 1) % 3;
            int n = BATCH * 4096;
            fc_lif_kernel<<<(n + 255) / 256, 256, 0, stream>>>(
                src, fc1, mfc1, bufs[d], thr, leak, 14, 4096, 4096, n);
            cur = d; src = bufs[cur];
        }
        fc2_acc_kernel<<<BATCH * 10, 64, 0, stream>>>(src, fc2, (float*)d_out, 4096, 10);
    }
}

// Round 2
// 7744.865 us; speedup vs baseline: 1.5312x; 1.5312x over previous
//
#include <hip/hip_runtime.h>

// VGG16-A spiking NN, multi-compartment LIF (K=2), T=3, B=4, fp32.
// Round 2: wave-per-output kernels (lane-split K reduction) for conv layers
// with IC>=64 and for FC layers. Fixes the latency-bound serial-chain problem
// seen in round 1 (Occupancy 3%, VALUBusy 0.9% on fc_lif).

#define BATCH 4

__device__ __forceinline__ float lif_update(float mem_in, float syn, float thr,
                                            float leak, float* mem_out) {
    float m = leak * mem_in + syn;
    float val = 0.f;
    if ((m / thr - 1.f > 0.f) && (1.f - m / (2.f * thr) >= 0.f)) val += 1.f;
    if ((m / (2.f * thr) - 1.f > 0.f) && (1.f - m / (4.f * thr) >= 0.f)) val += 2.f;
    *mem_out = m - thr * val;
    return val;
}

// Element-per-thread conv+LIF (used only for layer 0, IC=3).
__global__ void conv_lif_kernel(const float* __restrict__ in,
                                const float* __restrict__ w,
                                float* __restrict__ mem,
                                float* __restrict__ out,
                                const float* __restrict__ thr_v,
                                const float* __restrict__ leak_v,
                                int layer, int IC, int OC, int H, int W, int n) {
    int idx = blockIdx.x * blockDim.x + threadIdx.x;
    if (idx >= n) return;
    int x  = idx % W;
    int y  = (idx / W) % H;
    int oc = (idx / (W * H)) % OC;
    int b  = idx / (W * H * OC);

    const float* wp = w + (size_t)oc * IC * 9;
    const float* ip = in + (size_t)b * IC * H * W;

    float syn = 0.f;
    for (int ic = 0; ic < IC; ++ic) {
        const float* ipc = ip + (size_t)ic * H * W;
        const float* wpc = wp + ic * 9;
#pragma unroll
        for (int ky = 0; ky < 3; ++ky) {
            int yy = y + ky - 1;
            if (yy < 0 || yy >= H) continue;
#pragma unroll
            for (int kx = 0; kx < 3; ++kx) {
                int xx = x + kx - 1;
                if (xx < 0 || xx >= W) continue;
                syn = fmaf(ipc[yy * W + xx], wpc[ky * 3 + kx], syn);
            }
        }
    }
    float mo;
    float val = lif_update(mem[idx], syn, thr_v[layer], leak_v[layer], &mo);
    mem[idx] = mo;
    out[idx] = val;
}

// Wave-per-output conv+LIF: lane l reduces over ic = l, l+64, ... (IC>=64).
// y,x,oc are wave-uniform -> bounds branches are non-divergent.
__global__ void conv_lif_wave_kernel(const float* __restrict__ in,
                                     const float* __restrict__ w,
                                     float* __restrict__ mem,
                                     float* __restrict__ out,
                                     const float* __restrict__ thr_v,
                                     const float* __restrict__ leak_v,
                                     int layer, int IC, int OC, int H, int W,
                                     int n) {
    int wave = (blockIdx.x * blockDim.x + threadIdx.x) >> 6;
    int lane = threadIdx.x & 63;
    if (wave >= n) return;
    int x  = wave % W;
    int y  = (wave / W) % H;
    int oc = (wave / (W * H)) % OC;
    int b  = wave / (W * H * OC);

    float syn = 0.f;
    for (int ic = lane; ic < IC; ic += 64) {
        const float* ipc = in + ((size_t)(b * IC + ic)) * H * W;
        const float* wpc = w + ((size_t)oc * IC + ic) * 9;
#pragma unroll
        for (int ky = 0; ky < 3; ++ky) {
            int yy = y + ky - 1;
            if (yy < 0 || yy >= H) continue;
#pragma unroll
            for (int kx = 0; kx < 3; ++kx) {
                int xx = x + kx - 1;
                if (xx < 0 || xx >= W) continue;
                syn = fmaf(ipc[yy * W + xx], wpc[ky * 3 + kx], syn);
            }
        }
    }
#pragma unroll
    for (int off = 32; off > 0; off >>= 1) syn += __shfl_xor(syn, off);
    if (lane == 0) {
        float mo;
        float val = lif_update(mem[wave], syn, thr_v[layer], leak_v[layer], &mo);
        mem[wave] = mo;
        out[wave] = val;
    }
}

__global__ void avgpool_kernel(const float* __restrict__ in,
                               float* __restrict__ out,
                               int C, int Ho, int Wo, int n) {
    int idx = blockIdx.x * blockDim.x + threadIdx.x;
    if (idx >= n) return;
    int x = idx % Wo;
    int y = (idx / Wo) % Ho;
    int c = (idx / (Wo * Ho)) % C;
    int b = idx / (Wo * Ho * C);
    int Wi = Wo * 2, Hi = Ho * 2;
    const float* ip = in + ((size_t)b * C + c) * Hi * Wi;
    float s = ip[(2 * y) * Wi + 2 * x] + ip[(2 * y) * Wi + 2 * x + 1] +
              ip[(2 * y + 1) * Wi + 2 * x] + ip[(2 * y + 1) * Wi + 2 * x + 1];
    out[idx] = s * 0.25f;
}

// Wave-per-output-neuron FC+LIF: lanes split K (float4), weight row read once
// and reused for all 4 batch accumulators; butterfly reduce; lane 0 does LIF.
__global__ void fc_lif_wave_kernel(const float* __restrict__ in,
                                   const float* __restrict__ w,
                                   float* __restrict__ mem,
                                   float* __restrict__ out,
                                   const float* __restrict__ thr_v,
                                   const float* __restrict__ leak_v,
                                   int layer, int Kd, int N) {
    int wave = (blockIdx.x * blockDim.x + threadIdx.x) >> 6;
    int lane = threadIdx.x & 63;
    if (wave >= N) return;
    int j = wave;
    int K4 = Kd >> 2;
    const float4* wp = (const float4*)(w + (size_t)j * Kd);
    const float4* ip = (const float4*)in;
    float a0 = 0.f, a1 = 0.f, a2 = 0.f, a3 = 0.f;
    for (int k = lane; k < K4; k += 64) {
        float4 wv = wp[k];
        float4 v0 = ip[k];
        float4 v1 = ip[K4 + k];
        float4 v2 = ip[2 * K4 + k];
        float4 v3 = ip[3 * K4 + k];
        a0 = fmaf(wv.x, v0.x, fmaf(wv.y, v0.y, fmaf(wv.z, v0.z, fmaf(wv.w, v0.w, a0))));
        a1 = fmaf(wv.x, v1.x, fmaf(wv.y, v1.y, fmaf(wv.z, v1.z, fmaf(wv.w, v1.w, a1))));
        a2 = fmaf(wv.x, v2.x, fmaf(wv.y, v2.y, fmaf(wv.z, v2.z, fmaf(wv.w, v2.w, a2))));
        a3 = fmaf(wv.x, v3.x, fmaf(wv.y, v3.y, fmaf(wv.z, v3.z, fmaf(wv.w, v3.w, a3))));
    }
#pragma unroll
    for (int off = 32; off > 0; off >>= 1) {
        a0 += __shfl_xor(a0, off);
        a1 += __shfl_xor(a1, off);
        a2 += __shfl_xor(a2, off);
        a3 += __shfl_xor(a3, off);
    }
    if (lane == 0) {
        float thr = thr_v[layer], leak = leak_v[layer];
        float acc[4] = {a0, a1, a2, a3};
#pragma unroll
        for (int b = 0; b < BATCH; ++b) {
            float mo;
            float val = lif_update(mem[(size_t)b * N + j], acc[b], thr, leak, &mo);
            mem[(size_t)b * N + j] = mo;
            out[(size_t)b * N + j] = val;
        }
    }
}

// One 64-thread block per (b, label). logits += in[b,:] . w[l,:]
__global__ void fc2_acc_kernel(const float* __restrict__ in,
                               const float* __restrict__ w,
                               float* __restrict__ logits,
                               int Kd, int L) {
    int o = blockIdx.x;  // 0..B*L-1
    int l = o % L;
    int b = o / L;
    int K4 = Kd >> 2;
    const float4* ip = (const float4*)(in + (size_t)b * Kd);
    const float4* wp = (const float4*)(w + (size_t)l * Kd);
    float s = 0.f;
    for (int k = threadIdx.x; k < K4; k += 64) {
        float4 iv = ip[k];
        float4 wv = wp[k];
        s = fmaf(iv.x, wv.x, fmaf(iv.y, wv.y, fmaf(iv.z, wv.z, fmaf(iv.w, wv.w, s))));
    }
#pragma unroll
    for (int off = 32; off > 0; off >>= 1) s += __shfl_xor(s, off);
    if (threadIdx.x == 0) logits[o] += s;
}

extern "C" void kernel_launch(void* const* d_in, const int* in_sizes, int n_in,
                              void* d_out, int out_size, void* d_ws, size_t ws_size,
                              hipStream_t stream) {
    const float* x = (const float*)d_in[0];
    const float* convw[13];
    for (int i = 0; i < 13; ++i) convw[i] = (const float*)d_in[1 + i];
    const float* fc0 = (const float*)d_in[14];
    const float* fc1 = (const float*)d_in[15];
    const float* fc2 = (const float*)d_in[16];
    const float* thr = (const float*)d_in[17];
    const float* leak = (const float*)d_in[18];

    static const int IC[13] = {3, 64, 64, 128, 128, 256, 256, 256, 512, 512, 512, 512, 512};
    static const int OC[13] = {64, 64, 128, 128, 256, 256, 256, 512, 512, 512, 512, 512, 512};
    static const int HH[13] = {32, 32, 16, 16, 8, 8, 8, 4, 4, 4, 2, 2, 2};
    static const bool PA[13] = {false, true, false, true, false, false, true,
                                false, false, true, false, false, false};

    // workspace layout (floats)
    float* ws = (float*)d_ws;
    size_t off = 0;
    float* convmem[13];
    for (int i = 0; i < 13; ++i) {
        convmem[i] = ws + off;
        off += (size_t)BATCH * OC[i] * HH[i] * HH[i];
    }
    float* mfc0 = ws + off; off += BATCH * 4096;
    float* mfc1 = ws + off; off += BATCH * 4096;
    size_t mem_floats = off;
    float* bufs[3];
    for (int i = 0; i < 3; ++i) { bufs[i] = ws + off; off += 262144; }

    hipMemsetAsync(d_ws, 0, mem_floats * sizeof(float), stream);
    hipMemsetAsync(d_out, 0, (size_t)out_size * sizeof(float), stream);

    for (int t = 0; t < 3; ++t) {
        const float* src = x;
        int cur = -1;
        for (int i = 0; i < 13; ++i) {
            int d = (cur + 1) % 3;
            if (cur < 0) d = 0;
            int n = BATCH * OC[i] * HH[i] * HH[i];
            if (i == 0) {
                conv_lif_kernel<<<(n + 255) / 256, 256, 0, stream>>>(
                    src, convw[i], convmem[i], bufs[d], thr, leak, i,
                    IC[i], OC[i], HH[i], HH[i], n);
            } else {
                // one wave (64 lanes) per output element
                long long threads = (long long)n * 64;
                conv_lif_wave_kernel<<<(int)((threads + 255) / 256), 256, 0, stream>>>(
                    src, convw[i], convmem[i], bufs[d], thr, leak, i,
                    IC[i], OC[i], HH[i], HH[i], n);
            }
            cur = d; src = bufs[cur];
            if (PA[i]) {
                int p = (cur + 1) % 3;
                int Ho = HH[i] / 2;
                int np = BATCH * OC[i] * Ho * Ho;
                avgpool_kernel<<<(np + 255) / 256, 256, 0, stream>>>(
                    src, bufs[p], OC[i], Ho, Ho, np);
                cur = p; src = bufs[p];
            }
        }
        {
            int d = (cur + 1) % 3;
            fc_lif_wave_kernel<<<(4096 * 64) / 256, 256, 0, stream>>>(
                src, fc0, mfc0, bufs[d], thr, leak, 13, 2048, 4096);
            cur = d; src = bufs[cur];
        }
        {
            int d = (cur + 1) % 3;
            fc_lif_wave_kernel<<<(4096 * 64) / 256, 256, 0, stream>>>(
                src, fc1, mfc1, bufs[d], thr, leak, 14, 4096, 4096);
            cur = d; src = bufs[cur];
        }
        fc2_acc_kernel<<<BATCH * 10, 64, 0, stream>>>(src, fc2, (float*)d_out, 4096, 10);
    }
}

// Round 3
// 2254.407 us; speedup vs baseline: 5.2604x; 3.4354x over previous
//
#include <hip/hip_runtime.h>

// VGG16-A spiking NN, multi-compartment LIF (K=2), T=3, B=4, fp32.
// Round 3: conv restructure.
//  - conv_pix  (layers 1-6): lane = pixel (coalesced inputs), wave-uniform oc
//    group (scalar weight loads), OCT register accumulators, no reduction.
//  - conv_small (layers 7-12, 4x4/2x2): wave per oc, lanes split IC, spatial
//    plane in registers, butterfly transpose-reduce, parallel LIF epilogue.

#define BATCH 4

__device__ __forceinline__ float lif_update(float mem_in, float syn, float thr,
                                            float leak, float* mem_out) {
    float m = leak * mem_in + syn;
    float val = 0.f;
    if ((m / thr - 1.f > 0.f) && (1.f - m / (2.f * thr) >= 0.f)) val += 1.f;
    if ((m / (2.f * thr) - 1.f > 0.f) && (1.f - m / (4.f * thr) >= 0.f)) val += 2.f;
    *mem_out = m - thr * val;
    return val;
}

// Element-per-thread conv+LIF (layer 0 only, IC=3).
__global__ void conv_lif_kernel(const float* __restrict__ in,
                                const float* __restrict__ w,
                                float* __restrict__ mem,
                                float* __restrict__ out,
                                const float* __restrict__ thr_v,
                                const float* __restrict__ leak_v,
                                int layer, int IC, int OC, int H, int W, int n) {
    int idx = blockIdx.x * blockDim.x + threadIdx.x;
    if (idx >= n) return;
    int x  = idx % W;
    int y  = (idx / W) % H;
    int oc = (idx / (W * H)) % OC;
    int b  = idx / (W * H * OC);

    const float* wp = w + (size_t)oc * IC * 9;
    const float* ip = in + (size_t)b * IC * H * W;

    float syn = 0.f;
    for (int ic = 0; ic < IC; ++ic) {
        const float* ipc = ip + (size_t)ic * H * W;
        const float* wpc = wp + ic * 9;
#pragma unroll
        for (int ky = 0; ky < 3; ++ky) {
            int yy = y + ky - 1;
            if (yy < 0 || yy >= H) continue;
#pragma unroll
            for (int kx = 0; kx < 3; ++kx) {
                int xx = x + kx - 1;
                if (xx < 0 || xx >= W) continue;
                syn = fmaf(ipc[yy * W + xx], wpc[ky * 3 + kx], syn);
            }
        }
    }
    float mo;
    float val = lif_update(mem[idx], syn, thr_v[layer], leak_v[layer], &mo);
    mem[idx] = mo;
    out[idx] = val;
}

// Lane = pixel; wave covers 64 contiguous pixels (64/W rows). Wave-uniform
// (b, row-chunk, oc-group); OCT accumulators per lane; weights via uniform
// scalar loads. Grid must be exactly B * (H*W/64) * (OC/OCT) waves.
template <int OCT>
__global__ void conv_pix_kernel(const float* __restrict__ in,
                                const float* __restrict__ w,
                                float* __restrict__ mem,
                                float* __restrict__ out,
                                const float* __restrict__ thr_v,
                                const float* __restrict__ leak_v,
                                int layer, int IC, int OC, int H, int W) {
    int lane = threadIdx.x & 63;
    int wid = __builtin_amdgcn_readfirstlane(
        (int)((blockIdx.x * blockDim.x + threadIdx.x) >> 6));
    int ocg = OC / OCT;
    int HW = H * W;
    int chunks = HW >> 6;
    int g  = wid % ocg;
    int ch = (wid / ocg) % chunks;
    int b  = wid / (ocg * chunks);
    int rpw = 64 / W;  // rows per wave
    int y = ch * rpw + lane / W;
    int x = lane % W;
    int oc0 = g * OCT;

    // lane-constant neighborhood offsets + masks
    int off[9];
    bool msk[9];
#pragma unroll
    for (int ky = 0; ky < 3; ++ky)
#pragma unroll
        for (int kx = 0; kx < 3; ++kx) {
            int yy = y + ky - 1, xx = x + kx - 1;
            bool v = (yy >= 0 && yy < H && xx >= 0 && xx < W);
            msk[ky * 3 + kx] = v;
            off[ky * 3 + kx] = v ? yy * W + xx : 0;
        }

    float acc[OCT];
#pragma unroll
    for (int t = 0; t < OCT; ++t) acc[t] = 0.f;

    const float* ibase = in + (size_t)b * IC * HW;
    const float* wbase = w + (size_t)oc0 * IC * 9;

    for (int ic = 0; ic < IC; ++ic) {
        const float* ip = ibase + (size_t)ic * HW;
        float v[9];
#pragma unroll
        for (int k = 0; k < 9; ++k) v[k] = msk[k] ? ip[off[k]] : 0.f;
        const float* wp = wbase + (size_t)ic * 9;
#pragma unroll
        for (int t = 0; t < OCT; ++t) {
            const float* wt = wp + (size_t)t * IC * 9;
#pragma unroll
            for (int k = 0; k < 9; ++k) acc[t] = fmaf(v[k], wt[k], acc[t]);
        }
    }

    float thr = thr_v[layer], leak = leak_v[layer];
#pragma unroll
    for (int t = 0; t < OCT; ++t) {
        size_t idx = (size_t)(b * OC + oc0 + t) * HW + y * W + x;
        float mo;
        float val = lif_update(mem[idx], acc[t], thr, leak, &mo);
        mem[idx] = mo;
        out[idx] = val;
    }
}

// Wave per oc; lanes split IC (ic = lane + 64*i); whole S x S plane for all
// 4 batches kept in registers. Butterfly transpose-reduce: after log2(M)
// steps lane l owns output bitrev(l); parallel LIF epilogue.
template <int S>
__global__ void conv_small_kernel(const float* __restrict__ in,
                                  const float* __restrict__ w,
                                  float* __restrict__ mem,
                                  float* __restrict__ out,
                                  const float* __restrict__ thr_v,
                                  const float* __restrict__ leak_v,
                                  int layer, int IC, int OC) {
    constexpr int SS = S * S;
    constexpr int M = 4 * SS;              // 64 (S=4) or 16 (S=2)
    constexpr int LOG2M = (S == 4) ? 6 : 4;
    int lane = threadIdx.x & 63;
    int oc = __builtin_amdgcn_readfirstlane(
        (int)((blockIdx.x * blockDim.x + threadIdx.x) >> 6));

    float acc[M];
#pragma unroll
    for (int i = 0; i < M; ++i) acc[i] = 0.f;

    const float* wrow = w + (size_t)oc * IC * 9;
    int nic = IC >> 6;
    for (int i = 0; i < nic; ++i) {
        int ic = lane + (i << 6);
        const float* wp = wrow + (size_t)ic * 9;
        float wv[9];
#pragma unroll
        for (int k = 0; k < 9; ++k) wv[k] = wp[k];
#pragma unroll
        for (int b = 0; b < 4; ++b) {
            const float4* ip =
                (const float4*)(in + (size_t)(b * IC + ic) * SS);
            float pv[SS];
#pragma unroll
            for (int q = 0; q < SS / 4; ++q) {
                float4 t4 = ip[q];
                pv[4 * q + 0] = t4.x;
                pv[4 * q + 1] = t4.y;
                pv[4 * q + 2] = t4.z;
                pv[4 * q + 3] = t4.w;
            }
#pragma unroll
            for (int y = 0; y < S; ++y)
#pragma unroll
                for (int x = 0; x < S; ++x) {
                    float a = acc[b * SS + y * S + x];
#pragma unroll
                    for (int ky = 0; ky < 3; ++ky) {
                        int yy = y + ky - 1;
                        if (yy < 0 || yy >= S) continue;
#pragma unroll
                        for (int kx = 0; kx < 3; ++kx) {
                            int xx = x + kx - 1;
                            if (xx < 0 || xx >= S) continue;
                            a = fmaf(pv[yy * S + xx], wv[ky * 3 + kx], a);
                        }
                    }
                    acc[b * SS + y * S + x] = a;
                }
        }
    }

    // transpose-reduce: M accs across 64 lanes -> 1 value per lane
#pragma unroll
    for (int step = 0; step < LOG2M; ++step) {
        const int offx = 1 << step;
        const int half = M >> (step + 1);
        const bool hi = (lane & offx) != 0;
#pragma unroll
        for (int i = 0; i < half; ++i) {
            float sent = hi ? acc[i] : acc[i + half];
            float got = __shfl_xor(sent, offx);
            acc[i] = (hi ? acc[i + half] : acc[i]) + got;
        }
    }
    float sum = acc[0];
#pragma unroll
    for (int offx = M; offx < 64; offx <<= 1) sum += __shfl_xor(sum, offx);

    int o = (int)(__brev((unsigned)(lane & (M - 1))) >> (32 - LOG2M));
    if (lane < M) {
        int b = o / SS, p = o % SS;
        size_t idx = (size_t)(b * OC + oc) * SS + p;
        float mo;
        float val = lif_update(mem[idx], sum, thr_v[layer], leak_v[layer], &mo);
        mem[idx] = mo;
        out[idx] = val;
    }
}

__global__ void avgpool_kernel(const float* __restrict__ in,
                               float* __restrict__ out,
                               int C, int Ho, int Wo, int n) {
    int idx = blockIdx.x * blockDim.x + threadIdx.x;
    if (idx >= n) return;
    int x = idx % Wo;
    int y = (idx / Wo) % Ho;
    int c = (idx / (Wo * Ho)) % C;
    int b = idx / (Wo * Ho * C);
    int Wi = Wo * 2, Hi = Ho * 2;
    const float* ip = in + ((size_t)b * C + c) * Hi * Wi;
    float s = ip[(2 * y) * Wi + 2 * x] + ip[(2 * y) * Wi + 2 * x + 1] +
              ip[(2 * y + 1) * Wi + 2 * x] + ip[(2 * y + 1) * Wi + 2 * x + 1];
    out[idx] = s * 0.25f;
}

// Wave-per-output-neuron FC+LIF (float4 K-split, 4-batch reuse).
__global__ void fc_lif_wave_kernel(const float* __restrict__ in,
                                   const float* __restrict__ w,
                                   float* __restrict__ mem,
                                   float* __restrict__ out,
                                   const float* __restrict__ thr_v,
                                   const float* __restrict__ leak_v,
                                   int layer, int Kd, int N) {
    int wave = (blockIdx.x * blockDim.x + threadIdx.x) >> 6;
    int lane = threadIdx.x & 63;
    if (wave >= N) return;
    int j = wave;
    int K4 = Kd >> 2;
    const float4* wp = (const float4*)(w + (size_t)j * Kd);
    const float4* ip = (const float4*)in;
    float a0 = 0.f, a1 = 0.f, a2 = 0.f, a3 = 0.f;
    for (int k = lane; k < K4; k += 64) {
        float4 wv = wp[k];
        float4 v0 = ip[k];
        float4 v1 = ip[K4 + k];
        float4 v2 = ip[2 * K4 + k];
        float4 v3 = ip[3 * K4 + k];
        a0 = fmaf(wv.x, v0.x, fmaf(wv.y, v0.y, fmaf(wv.z, v0.z, fmaf(wv.w, v0.w, a0))));
        a1 = fmaf(wv.x, v1.x, fmaf(wv.y, v1.y, fmaf(wv.z, v1.z, fmaf(wv.w, v1.w, a1))));
        a2 = fmaf(wv.x, v2.x, fmaf(wv.y, v2.y, fmaf(wv.z, v2.z, fmaf(wv.w, v2.w, a2))));
        a3 = fmaf(wv.x, v3.x, fmaf(wv.y, v3.y, fmaf(wv.z, v3.z, fmaf(wv.w, v3.w, a3))));
    }
#pragma unroll
    for (int off = 32; off > 0; off >>= 1) {
        a0 += __shfl_xor(a0, off);
        a1 += __shfl_xor(a1, off);
        a2 += __shfl_xor(a2, off);
        a3 += __shfl_xor(a3, off);
    }
    if (lane == 0) {
        float thr = thr_v[layer], leak = leak_v[layer];
        float accv[4] = {a0, a1, a2, a3};
#pragma unroll
        for (int b = 0; b < BATCH; ++b) {
            float mo;
            float val = lif_update(mem[(size_t)b * N + j], accv[b], thr, leak, &mo);
            mem[(size_t)b * N + j] = mo;
            out[(size_t)b * N + j] = val;
        }
    }
}

// One 64-thread block per (b, label). logits += in[b,:] . w[l,:]
__global__ void fc2_acc_kernel(const float* __restrict__ in,
                               const float* __restrict__ w,
                               float* __restrict__ logits,
                               int Kd, int L) {
    int o = blockIdx.x;
    int l = o % L;
    int b = o / L;
    int K4 = Kd >> 2;
    const float4* ip = (const float4*)(in + (size_t)b * Kd);
    const float4* wp = (const float4*)(w + (size_t)l * Kd);
    float s = 0.f;
    for (int k = threadIdx.x; k < K4; k += 64) {
        float4 iv = ip[k];
        float4 wv = wp[k];
        s = fmaf(iv.x, wv.x, fmaf(iv.y, wv.y, fmaf(iv.z, wv.z, fmaf(iv.w, wv.w, s))));
    }
#pragma unroll
    for (int off = 32; off > 0; off >>= 1) s += __shfl_xor(s, off);
    if (threadIdx.x == 0) logits[o] += s;
}

extern "C" void kernel_launch(void* const* d_in, const int* in_sizes, int n_in,
                              void* d_out, int out_size, void* d_ws, size_t ws_size,
                              hipStream_t stream) {
    const float* x = (const float*)d_in[0];
    const float* convw[13];
    for (int i = 0; i < 13; ++i) convw[i] = (const float*)d_in[1 + i];
    const float* fc0 = (const float*)d_in[14];
    const float* fc1 = (const float*)d_in[15];
    const float* fc2 = (const float*)d_in[16];
    const float* thr = (const float*)d_in[17];
    const float* leak = (const float*)d_in[18];

    static const int IC[13] = {3, 64, 64, 128, 128, 256, 256, 256, 512, 512, 512, 512, 512};
    static const int OC[13] = {64, 64, 128, 128, 256, 256, 256, 512, 512, 512, 512, 512, 512};
    static const int HH[13] = {32, 32, 16, 16, 8, 8, 8, 4, 4, 4, 2, 2, 2};
    static const bool PA[13] = {false, true, false, true, false, false, true,
                                false, false, true, false, false, false};

    float* ws = (float*)d_ws;
    size_t off = 0;
    float* convmem[13];
    for (int i = 0; i < 13; ++i) {
        convmem[i] = ws + off;
        off += (size_t)BATCH * OC[i] * HH[i] * HH[i];
    }
    float* mfc0 = ws + off; off += BATCH * 4096;
    float* mfc1 = ws + off; off += BATCH * 4096;
    size_t mem_floats = off;
    float* bufs[3];
    for (int i = 0; i < 3; ++i) { bufs[i] = ws + off; off += 262144; }

    hipMemsetAsync(d_ws, 0, mem_floats * sizeof(float), stream);
    hipMemsetAsync(d_out, 0, (size_t)out_size * sizeof(float), stream);

    for (int t = 0; t < 3; ++t) {
        const float* src = x;
        int cur = -1;
        for (int i = 0; i < 13; ++i) {
            int d = (cur + 1) % 3;
            if (cur < 0) d = 0;
            int H = HH[i], W = HH[i];
            if (i == 0) {
                int n = BATCH * OC[i] * H * W;
                conv_lif_kernel<<<(n + 255) / 256, 256, 0, stream>>>(
                    src, convw[i], convmem[i], bufs[d], thr, leak, i,
                    IC[i], OC[i], H, W, n);
            } else if (H >= 8) {
                // conv_pix: OCT=8 for layer 1, OCT=4 for layers 2-6
                if (i == 1) {
                    const int OCT = 8;
                    int waves = BATCH * (H * W / 64) * (OC[i] / OCT);
                    conv_pix_kernel<OCT><<<waves * 64 / 256, 256, 0, stream>>>(
                        src, convw[i], convmem[i], bufs[d], thr, leak, i,
                        IC[i], OC[i], H, W);
                } else {
                    const int OCT = 4;
                    int waves = BATCH * (H * W / 64) * (OC[i] / OCT);
                    conv_pix_kernel<OCT><<<waves * 64 / 256, 256, 0, stream>>>(
                        src, convw[i], convmem[i], bufs[d], thr, leak, i,
                        IC[i], OC[i], H, W);
                }
            } else if (H == 4) {
                conv_small_kernel<4><<<OC[i] * 64 / 256, 256, 0, stream>>>(
                    src, convw[i], convmem[i], bufs[d], thr, leak, i, IC[i], OC[i]);
            } else {  // H == 2
                conv_small_kernel<2><<<OC[i] * 64 / 256, 256, 0, stream>>>(
                    src, convw[i], convmem[i], bufs[d], thr, leak, i, IC[i], OC[i]);
            }
            cur = d; src = bufs[cur];
            if (PA[i]) {
                int p = (cur + 1) % 3;
                int Ho = HH[i] / 2;
                int np = BATCH * OC[i] * Ho * Ho;
                avgpool_kernel<<<(np + 255) / 256, 256, 0, stream>>>(
                    src, bufs[p], OC[i], Ho, Ho, np);
                cur = p; src = bufs[p];
            }
        }
        {
            int d = (cur + 1) % 3;
            fc_lif_wave_kernel<<<(4096 * 64) / 256, 256, 0, stream>>>(
                src, fc0, mfc0, bufs[d], thr, leak, 13, 2048, 4096);
            cur = d; src = bufs[cur];
        }
        {
            int d = (cur + 1) % 3;
            fc_lif_wave_kernel<<<(4096 * 64) / 256, 256, 0, stream>>>(
                src, fc1, mfc1, bufs[d], thr, leak, 14, 4096, 4096);
            cur = d; src = bufs[cur];
        }
        fc2_acc_kernel<<<BATCH * 10, 64, 0, stream>>>(src, fc2, (float*)d_out, 4096, 10);
    }
}